// Round 1
// 715.267 us; speedup vs baseline: 1.0971x; 1.0971x over previous
//
#include <hip/hip_runtime.h>
#include <hip/hip_bf16.h>
#include <math.h>

typedef unsigned short u16;
typedef float fx4 __attribute__((ext_vector_type(4)));
typedef __bf16 bx8 __attribute__((ext_vector_type(8)));

constexpr int BB  = 8;
constexpr int HH  = 256;
constexpr int LL  = 8192;
constexpr int NN  = 16;
constexpr int DTE = 512;
constexpr int SC  = 64;     // chunk length for the scan (W^SC used in phase 3)
constexpr int CHN = 128;    // number of chunks per row
constexpr int HN  = HH * NN;

constexpr size_t BHL = (size_t)BB * HH * LL;

constexpr int OFF_WR  = 0;
constexpr int OFF_WI  = HN;
constexpr int OFF_WSR = 2 * HN;
constexpr int OFF_WSI = 3 * HN;
constexpr int OFF_C0R = 4 * HN;
constexpr int OFF_C0I = 5 * HN;
constexpr int OFF_C1R = 6 * HN;
constexpr int OFF_C1I = 7 * HN;
constexpr int OFF_PT  = 8 * HN;

__device__ __forceinline__ float gelu_tanh(float x) {
    float x3 = x * x * x;
    float y = 1.5957691216057308f * x + 0.07135481627767453f * x3;
    return x / (1.0f + __expf(-y));
}
__device__ __forceinline__ float sigmoid_(float x) {
    return 1.0f / (1.0f + __expf(-x));
}
__device__ __forceinline__ __hip_bfloat16 f2b(float x) { return __float2bfloat16(x); }
__device__ __forceinline__ float b2f(__hip_bfloat16 x) { return __bfloat162float(x); }
__device__ __forceinline__ u16 f2us(float x) {
    __hip_bfloat16 b = __float2bfloat16(x);
    return *reinterpret_cast<u16*>(&b);
}
__device__ __forceinline__ float lo2f(unsigned v) { return __uint_as_float(v << 16); }
__device__ __forceinline__ float hi2f(unsigned v) { return __uint_as_float(v & 0xffff0000u); }
__device__ __forceinline__ unsigned pack2(float a, float b) {
    return (unsigned)f2us(a) | ((unsigned)f2us(b) << 16);
}

__global__ void setup_s4_params(const float* __restrict__ log_dt,
                                const float* __restrict__ A_re,
                                const float* __restrict__ A_im,
                                const float* __restrict__ C_re,
                                const float* __restrict__ C_im,
                                float* __restrict__ P) {
    int idx = blockIdx.x * blockDim.x + threadIdx.x;
    if (idx >= HN) return;
    int h = idx >> 4;
    double dt = exp((double)log_dt[h]);
    double Ar = (double)A_re[idx], Ai = (double)A_im[idx];
    double dr = Ar * dt, di = Ai * dt;
    double e1 = exp(dr);
    double wr = e1 * cos(di), wi = e1 * sin(di);
    double eS = exp(dr * SC);
    double wSr = eS * cos(di * SC), wSi = eS * sin(di * SC);
    double d2 = Ar * Ar + Ai * Ai;
    double nr = wr - 1.0, ni = wi;
    double rr = (nr * Ar + ni * Ai) / d2;
    double ri = (ni * Ar - nr * Ai) / d2;
    double c0r = (double)C_re[idx],        c0i = (double)C_im[idx];
    double c1r = (double)C_re[HN + idx],   c1i = (double)C_im[HN + idx];
    P[OFF_WR  + idx] = (float)wr;
    P[OFF_WI  + idx] = (float)wi;
    P[OFF_WSR + idx] = (float)wSr;
    P[OFF_WSI + idx] = (float)wSi;
    P[OFF_C0R + idx] = (float)(2.0 * (c0r * rr - c0i * ri));
    P[OFF_C0I + idx] = (float)(2.0 * (c0r * ri + c0i * rr));
    P[OFF_C1R + idx] = (float)(2.0 * (c1r * rr - c1i * ri));
    P[OFF_C1I + idx] = (float)(2.0 * (c1r * ri + c1i * rr));
}

__global__ void part_t_kernel(const float* __restrict__ emb,
                              const float* __restrict__ w,
                              const float* __restrict__ bias,
                              float* __restrict__ P) {
    int idx = blockIdx.x * blockDim.x + threadIdx.x;
    if (idx >= BB * HH) return;
    int b = idx / HH, h = idx % HH;
    float s = bias[h];
    const float* er = emb + (size_t)b * DTE;
    const float* wr = w + (size_t)h * DTE;
    for (int e = 0; e < DTE; ++e) s = fmaf(er[e], wr[e], s);
    P[OFF_PT + idx] = s;
}

__global__ void convert_w_kernel(const float* __restrict__ src, u16* __restrict__ dst, int n) {
    int i = blockIdx.x * 256 + threadIdx.x;
    if (i < n) dst[i] = f2us(src[i]);
}

__global__ void tln_kernel(const float* __restrict__ in, float* __restrict__ out,
                           const float* __restrict__ mptr, const float* __restrict__ sptr,
                           const float* __restrict__ part_t) {
    int b = blockIdx.y;
    int l0 = blockIdx.x * 64;
    int t = threadIdx.x;
    int q = t >> 6, li = t & 63;
    const float* base = in + (size_t)b * HH * LL + l0 + li;
    float sum = 0.f, sq = 0.f;
    for (int i = 0; i < 64; ++i) {
        float v = base[(size_t)(q * 64 + i) * LL];
        sum += v; sq = fmaf(v, v, sq);
    }
    __shared__ float rs[4][64], rq[4][64], meanS[64], scaleS[64];
    rs[q][li] = sum; rq[q][li] = sq;
    __syncthreads();
    if (q == 0) {
        float s  = rs[0][li] + rs[1][li] + rs[2][li] + rs[3][li];
        float s2 = rq[0][li] + rq[1][li] + rq[2][li] + rq[3][li];
        float mean = s * (1.f / 256.f);
        float var  = fmaxf(s2 * (1.f / 256.f) - mean * mean, 0.f);
        meanS[li]  = mean;
        scaleS[li] = sptr[0] / sqrtf(var);
    }
    __syncthreads();
    float mean = meanS[li], scale = scaleS[li], m = mptr[0];
    float* ob = out + (size_t)b * HH * LL + l0 + li;
    for (int i = 0; i < 64; ++i) {
        int h = q * 64 + i;
        float v = base[(size_t)h * LL];
        float y = scale * (v - mean + m) + part_t[b * HH + h];
        ob[(size_t)h * LL] = y;
    }
}

__global__ void tln2t_kernel(const float* __restrict__ in, u16* __restrict__ outT,
                             const float* __restrict__ mptr, const float* __restrict__ sptr) {
    int b = blockIdx.y;
    int l0 = blockIdx.x * 64;
    int t = threadIdx.x;
    int q = t >> 6, li = t & 63;
    const float* base = in + (size_t)b * HH * LL + l0 + li;
    float sum = 0.f, sq = 0.f;
    for (int i = 0; i < 64; ++i) {
        float v = base[(size_t)(q * 64 + i) * LL];
        sum += v; sq = fmaf(v, v, sq);
    }
    __shared__ float rs[4][64], rq[4][64], meanS[64], scaleS[64];
    __shared__ u16 TT[64 * 262];
    rs[q][li] = sum; rq[q][li] = sq;
    __syncthreads();
    if (q == 0) {
        float s  = rs[0][li] + rs[1][li] + rs[2][li] + rs[3][li];
        float s2 = rq[0][li] + rq[1][li] + rq[2][li] + rq[3][li];
        float mean = s * (1.f / 256.f);
        float var  = fmaxf(s2 * (1.f / 256.f) - mean * mean, 0.f);
        meanS[li]  = mean;
        scaleS[li] = sptr[0] / sqrtf(var);
    }
    __syncthreads();
    float mean = meanS[li], scale = scaleS[li], m = mptr[0];
    for (int i = 0; i < 64; ++i) {
        int h = q * 64 + i;
        float v = base[(size_t)h * LL];
        TT[li * 262 + h] = f2us(scale * (v - mean + m));
    }
    __syncthreads();
    #pragma unroll
    for (int i = 0; i < 32; ++i) {
        int idx = t + i * 256;
        int c = idx & 127, l = idx >> 7;
        unsigned int v = *(const unsigned int*)&TT[l * 262 + 2 * c];
        *(unsigned int*)&outT[((size_t)b * LL + l0 + l) * 256 + 2 * c] = v;
    }
}

// ---- scan: 128 chunks x 64 elements per (b,h) row.
// Thread map for heavy phases: c = tid & 127 (chunk), dir = tid >> 7 (fwd/bwd),
// each thread owns all 16 states -> all 4 waves busy in phases 2 and 4.
constexpr int SUP  = 65;    // floats per chunk row (odd -> conflict-free column reads)
constexpr int FINP = 258;   // bf16 per fin row: 2*128 + 2 pad

__global__ __launch_bounds__(256, 3) void scan_fused(
    const float* __restrict__ uIn, const float* __restrict__ P,
    const float* __restrict__ Dp, float* __restrict__ ys)
{
    __shared__ __align__(16) float          su[CHN * SUP];     // 33280 B
    __shared__ __align__(16) __hip_bfloat16 ybuf[CHN * SUP];   // 16640 B
    // fin (carry buffer, 32*258 bf16 = 16512 B) aliases ybuf; dead before ybuf writes
    __hip_bfloat16* fin = ybuf;

    const int bh  = blockIdx.x;
    const int h   = bh & (HH - 1);
    const int tid = threadIdx.x;
    const float* urow = uIn + (size_t)bh * LL;
    float* yrow = ys + (size_t)bh * LL;

    // phase 1: stage u -> LDS (scalar writes; stride-65 rows)
    {
        const float4* u4 = (const float4*)urow;
        #pragma unroll
        for (int i = 0; i < 8; ++i) {
            int e4 = tid + i * 256;
            float4 v = u4[e4];
            int g = e4 << 2;
            int cc = g >> 6, j = g & 63;
            float* p = &su[cc * SUP + j];
            p[0] = v.x; p[1] = v.y; p[2] = v.z; p[3] = v.w;
        }
    }

    const int c   = tid & 127;
    const int dir = tid >> 7;

    // block-uniform coefficients (scalarized: h is uniform)
    float wr[NN], wi[NN];
    #pragma unroll
    for (int n = 0; n < NN; ++n) {
        wr[n] = P[OFF_WR + h * NN + n];
        wi[n] = P[OFF_WI + h * NN + n];
    }
    __syncthreads();

    // phase 2: per-chunk local end states (all 256 threads, 16 states each)
    {
        float fr[NN], fi[NN];
        #pragma unroll
        for (int n = 0; n < NN; ++n) { fr[n] = 0.f; fi[n] = 0.f; }
        const float* scp = &su[c * SUP];
        if (dir == 0) {
            for (int j = 0; j < 64; ++j) {
                float uv = scp[j];
                #pragma unroll
                for (int n = 0; n < NN; ++n) {
                    float nr = fmaf(wr[n], fr[n], fmaf(-wi[n], fi[n], uv));
                    float ni = fmaf(wr[n], fi[n], wi[n] * fr[n]);
                    fr[n] = nr; fi[n] = ni;
                }
            }
        } else {
            for (int j = 63; j >= 0; --j) {
                float uv = scp[j];
                #pragma unroll
                for (int n = 0; n < NN; ++n) {
                    float nr = fmaf(wr[n], fr[n], fmaf(-wi[n], fi[n], uv));
                    float ni = fmaf(wr[n], fi[n], wi[n] * fr[n]);
                    fr[n] = nr; fi[n] = ni;
                }
            }
        }
        #pragma unroll
        for (int n = 0; n < NN; ++n)
            *(unsigned*)&fin[(dir * NN + n) * FINP + 2 * c] = pack2(fr[n], fi[n]);
    }
    __syncthreads();

    // phase 3: serial scan over 128 chunk carries (32 threads)
    if (tid < 32) {
        const int d3 = tid >> 4, n = tid & 15;
        float wSr = P[OFF_WSR + h * NN + n], wSi = P[OFF_WSI + h * NN + n];
        __hip_bfloat16* fb = &fin[(d3 * NN + n) * FINP];
        float cr = 0.f, ci = 0.f;
        if (d3 == 0) {
            for (int q = 0; q < CHN; ++q) {
                unsigned pv = *(unsigned*)&fb[2 * q];
                float fr = lo2f(pv), fi = hi2f(pv);
                *(unsigned*)&fb[2 * q] = pack2(cr, ci);
                float nr2 = fmaf(wSr, cr, fmaf(-wSi, ci, fr));
                float ni2 = fmaf(wSr, ci, fmaf(wSi, cr, fi));
                cr = nr2; ci = ni2;
            }
        } else {
            for (int q = CHN - 1; q >= 0; --q) {
                unsigned pv = *(unsigned*)&fb[2 * q];
                float fr = lo2f(pv), fi = hi2f(pv);
                *(unsigned*)&fb[2 * q] = pack2(cr, ci);
                float nr2 = fmaf(wSr, cr, fmaf(-wSi, ci, fr));
                float ni2 = fmaf(wSr, ci, fmaf(wSi, cr, fi));
                cr = nr2; ci = ni2;
            }
        }
    }
    __syncthreads();

    // phase 4 init: load C and carries (fin still live here)
    float cr16[NN], ci16[NN], sr[NN], si[NN];
    {
        const int cO = dir ? OFF_C1R : OFF_C0R;
        const int cI = dir ? OFF_C1I : OFF_C0I;
        #pragma unroll
        for (int n = 0; n < NN; ++n) {
            cr16[n] = P[cO + h * NN + n];
            ci16[n] = P[cI + h * NN + n];
            unsigned pv = *(const unsigned*)&fin[(dir * NN + n) * FINP + 2 * c];
            sr[n] = lo2f(pv); si[n] = hi2f(pv);
        }
    }
    __syncthreads();   // fin consumed; ybuf region may now be overwritten

    float* sc = &su[c * SUP];
    __hip_bfloat16* yc = &ybuf[c * SUP];
    const float Dh = Dp[h];
    float ucur = 0.f;

    // phase 4a: partial y for own half of the chunk
    if (dir == 0) {
        for (int j = 0; j < 32; ++j) {
            float uv = sc[j];
            float acc = 0.f;
            #pragma unroll
            for (int n = 0; n < NN; ++n) {
                float nr = fmaf(wr[n], sr[n], fmaf(-wi[n], si[n], uv));
                float ni = fmaf(wr[n], si[n], wi[n] * sr[n]);
                sr[n] = nr; si[n] = ni;
                acc = fmaf(cr16[n], nr, fmaf(-ci16[n], ni, acc));
            }
            yc[j] = f2b(acc);
        }
    } else {
        {
            float acc = 0.f;
            #pragma unroll
            for (int n = 0; n < NN; ++n)
                acc = fmaf(cr16[n], sr[n], fmaf(-ci16[n], si[n], acc));
            yc[63] = f2b(acc);
        }
        for (int t = 63; t >= 33; --t) {
            float uv = sc[t];
            float acc = 0.f;
            #pragma unroll
            for (int n = 0; n < NN; ++n) {
                float nr = fmaf(wr[n], sr[n], fmaf(-wi[n], si[n], uv));
                float ni = fmaf(wr[n], si[n], wi[n] * sr[n]);
                sr[n] = nr; si[n] = ni;
                acc = fmaf(cr16[n], nr, fmaf(-ci16[n], ni, acc));
            }
            yc[t - 1] = f2b(acc);
        }
        ucur = sc[32];
    }
    __syncthreads();

    // phase 4b: finalize other half (own acc + other dir's partial + u*D, gelu)
    if (dir == 0) {
        for (int j = 32; j < 64; ++j) {
            float uv = sc[j];
            float acc = 0.f;
            #pragma unroll
            for (int n = 0; n < NN; ++n) {
                float nr = fmaf(wr[n], sr[n], fmaf(-wi[n], si[n], uv));
                float ni = fmaf(wr[n], si[n], wi[n] * sr[n]);
                sr[n] = nr; si[n] = ni;
                acc = fmaf(cr16[n], nr, fmaf(-ci16[n], ni, acc));
            }
            float tot = acc + b2f(yc[j]) + uv * Dh;
            sc[j] = gelu_tanh(tot);
        }
    } else {
        for (int t = 32; t >= 1; --t) {
            float acc = 0.f;
            #pragma unroll
            for (int n = 0; n < NN; ++n) {
                float nr = fmaf(wr[n], sr[n], fmaf(-wi[n], si[n], ucur));
                float ni = fmaf(wr[n], si[n], wi[n] * sr[n]);
                sr[n] = nr; si[n] = ni;
                acc = fmaf(cr16[n], nr, fmaf(-ci16[n], ni, acc));
            }
            float un = sc[t - 1];
            float tot = acc + b2f(yc[t - 1]) + un * Dh;
            sc[t - 1] = gelu_tanh(tot);
            ucur = un;
        }
    }
    __syncthreads();

    // phase 5: write back (scalar LDS reads, vector global stores)
    {
        #pragma unroll
        for (int i = 0; i < 8; ++i) {
            int e4 = tid + i * 256;
            int g = e4 << 2;
            int c2 = g >> 6, j = g & 63;
            const float* p = &su[c2 * SUP + j];
            float4 v;
            v.x = p[0]; v.y = p[1]; v.z = p[2]; v.w = p[3];
            ((float4*)yrow)[e4] = v;
        }
    }
}

__global__ void gemm_glu_kernel(const float* __restrict__ X, const float* __restrict__ W,
                                const float* __restrict__ bias, const float* __restrict__ xres,
                                float* __restrict__ out) {
    __shared__ __align__(16) float Xs[32][68];
    __shared__ __align__(16) float W0s[32][68];
    __shared__ __align__(16) float W1s[32][68];
    int b = blockIdx.z;
    int l0 = blockIdx.x * 64;
    int c0 = blockIdx.y * 64;
    int t = threadIdx.x, tx = t & 15, ty = t >> 4;
    float acc0[4][4] = {}, acc1[4][4] = {};
    const float* Xb = X + (size_t)b * HH * LL;
    for (int k0 = 0; k0 < HH; k0 += 32) {
        #pragma unroll
        for (int i = 0; i < 8; ++i) {
            int idx = t + i * 256, k = idx >> 6, l = idx & 63;
            Xs[k][l] = Xb[(size_t)(k0 + k) * LL + l0 + l];
        }
        {
            int o = t >> 2, kk = (t & 3) * 8;
            const float* wp0 = W + (size_t)(c0 + o) * HH + k0 + kk;
            const float* wp1 = W + (size_t)(c0 + 256 + o) * HH + k0 + kk;
            #pragma unroll
            for (int j = 0; j < 8; ++j) { W0s[kk + j][o] = wp0[j]; W1s[kk + j][o] = wp1[j]; }
        }
        __syncthreads();
        #pragma unroll
        for (int k = 0; k < 32; ++k) {
            float4 xv = *(const float4*)&Xs[k][tx * 4];
            float4 w0 = *(const float4*)&W0s[k][ty * 4];
            float4 w1 = *(const float4*)&W1s[k][ty * 4];
            const float* xp = &xv.x; const float* p0 = &w0.x; const float* p1 = &w1.x;
            #pragma unroll
            for (int i = 0; i < 4; ++i)
                #pragma unroll
                for (int j = 0; j < 4; ++j) {
                    acc0[i][j] = fmaf(p0[i], xp[j], acc0[i][j]);
                    acc1[i][j] = fmaf(p1[i], xp[j], acc1[i][j]);
                }
        }
        __syncthreads();
    }
    #pragma unroll
    for (int i = 0; i < 4; ++i) {
        int c = c0 + ty * 4 + i;
        float b0 = bias[c], b1 = bias[c + 256];
        float4 xr = *(const float4*)&xres[((size_t)b * HH + c) * LL + l0 + tx * 4];
        float4 ov;
        #pragma unroll
        for (int j = 0; j < 4; ++j) {
            float z0 = acc0[i][j] + b0;
            float z1 = acc1[i][j] + b1;
            (&ov.x)[j] = z0 * sigmoid_(z1) + (&xr.x)[j];
        }
        *(float4*)&out[((size_t)b * HH + c) * LL + l0 + tx * 4] = ov;
    }
}

template<int MODE, int WLD>
__global__ __launch_bounds__(256, 3) void gemm_mfma(
    const u16* __restrict__ Aw, const u16* __restrict__ Bm,
    const float* bias, const float* resid, void* outv)
{
    __shared__ __align__(16) char smem[33792];
    u16*   Alds = (u16*)smem;
    u16*   Blds = (u16*)(smem + 16384);
    float* Eps  = (float*)smem;
    u16*   TT   = (u16*)smem;

    const int tid  = threadIdx.x;
    const int lane = tid & 63;
    const int wv   = tid >> 6;
    const int wr   = wv >> 1, wc = wv & 1;
    const int bz   = blockIdx.z;
    const int l0   = blockIdx.x * 128;
    const int mbase = blockIdx.y * 128;

    fx4 acc[4][4];
    #pragma unroll
    for (int i = 0; i < 4; ++i)
        #pragma unroll
        for (int j = 0; j < 4; ++j) {
            fx4 z = {0.f, 0.f, 0.f, 0.f};
            acc[i][j] = z;
        }

    const size_t brow0 = (size_t)bz * LL;
    for (int k0 = 0; k0 < 256; k0 += 64) {
        #pragma unroll
        for (int i = 0; i < 4; ++i) {
            int f = tid + i * 256;
            int mm = f & 15, kg = (f >> 4) & 3, m16 = (f >> 6) & 7, ks = f >> 9;
            int k = k0 + ks * 32 + kg * 8;
            int o = mbase + m16 * 16 + mm;
            int4 wv4 = *(const int4*)(Aw + (size_t)o * WLD + k);
            *(int4*)&Alds[f * 8] = wv4;
            int row = l0 + m16 * 16 + mm;
            int4 xv4 = *(const int4*)(Bm + (brow0 + row) * 256 + k);
            *(int4*)&Blds[f * 8] = xv4;
        }
        __syncthreads();
        #pragma unroll
        for (int ks = 0; ks < 2; ++ks) {
            bx8 av[4], bv[4];
            #pragma unroll
            for (int mt = 0; mt < 4; ++mt)
                av[mt] = *(const bx8*)&Alds[(ks * 512 + (wr * 4 + mt) * 64 + lane) * 8];
            #pragma unroll
            for (int nt = 0; nt < 4; ++nt)
                bv[nt] = *(const bx8*)&Blds[(ks * 512 + (wc * 4 + nt) * 64 + lane) * 8];
            #pragma unroll
            for (int mt = 0; mt < 4; ++mt)
                #pragma unroll
                for (int nt = 0; nt < 4; ++nt)
                    acc[mt][nt] = __builtin_amdgcn_mfma_f32_16x16x32_bf16(
                        av[mt], bv[nt], acc[mt][nt], 0, 0, 0);
        }
        __syncthreads();
    }

    if (MODE == 1) {
        u16* hT = (u16*)outv;
        #pragma unroll
        for (int p = 0; p < 2; ++p) {
            if (p) __syncthreads();
            if (wc == p) {
                #pragma unroll
                for (int mt = 0; mt < 4; ++mt) {
                    int mb = wr * 64 + mt * 16 + (lane >> 4) * 4;
                    float bvv[4];
                    #pragma unroll
                    for (int r = 0; r < 4; ++r) bvv[r] = bias[mbase + mb + r];
                    #pragma unroll
                    for (int nt = 0; nt < 4; ++nt) {
                        int n = nt * 16 + (lane & 15);
                        u16 pk[4];
                        #pragma unroll
                        for (int r = 0; r < 4; ++r)
                            pk[r] = f2us(gelu_tanh(acc[mt][nt][r] + bvv[r]));
                        *(ushort4*)&TT[n * 136 + mb] = *(const ushort4*)pk;
                    }
                }
            }
            __syncthreads();
            #pragma unroll
            for (int i = 0; i < 4; ++i) {
                int idx = tid + i * 256;
                int l = idx >> 4, c = idx & 15;
                int4 v = *(const int4*)&TT[l * 136 + c * 8];
                *(int4*)&hT[((size_t)bz * LL + l0 + p * 64 + l) * 256 + mbase + c * 8] = v;
            }
        }
    } else {
        float* outp = (float*)outv;
        #pragma unroll
        for (int p = 0; p < 2; ++p) {
            if (p) __syncthreads();
            if (wc == p) {
                #pragma unroll
                for (int mt = 0; mt < 4; ++mt)
                    #pragma unroll
                    for (int nt = 0; nt < 4; ++nt) {
                        int m = wr * 64 + mt * 16 + (lane >> 4) * 4;
                        int n = nt * 16 + (lane & 15);
                        #pragma unroll
                        for (int r = 0; r < 4; ++r)
                            Eps[(m + r) * 66 + n] = acc[mt][nt][r];
                    }
            }
            __syncthreads();
            #pragma unroll
            for (int i = 0; i < 8; ++i) {
                int idx = tid + i * 256;
                int r = idx >> 4, lq = idx & 15;
                float bv = bias ? bias[mbase + r] : 0.f;
                size_t ga = ((size_t)bz * HH + mbase + r) * LL + l0 + p * 64 + lq * 4;
                float4 rv = *(const float4*)&resid[ga];
                float4 ov;
                #pragma unroll
                for (int j = 0; j < 4; ++j)
                    (&ov.x)[j] = Eps[r * 66 + lq * 4 + j] + bv + (&rv.x)[j];
                *(float4*)&outp[ga] = ov;
            }
        }
    }
}

extern "C" void kernel_launch(void* const* d_in, const int* in_sizes, int n_in,
                              void* d_out, int out_size, void* d_ws, size_t ws_size,
                              hipStream_t stream) {
    (void)in_sizes; (void)n_in; (void)out_size; (void)ws_size;
    const float* x      = (const float*)d_in[0];
    const float* emb    = (const float*)d_in[1];
    const float* fc_t_w = (const float*)d_in[2];
    const float* fc_t_b = (const float*)d_in[3];
    const float* log_dt = (const float*)d_in[4];
    const float* A_re   = (const float*)d_in[5];
    const float* A_im   = (const float*)d_in[6];
    const float* C_re   = (const float*)d_in[7];
    const float* C_im   = (const float*)d_in[8];
    const float* Dp     = (const float*)d_in[9];
    const float* out_w  = (const float*)d_in[10];
    const float* out_b  = (const float*)d_in[11];
    const float* n1_m   = (const float*)d_in[12];
    const float* n1_s   = (const float*)d_in[13];
    const float* n2_m   = (const float*)d_in[14];
    const float* n2_s   = (const float*)d_in[15];
    const float* ff_w1  = (const float*)d_in[16];
    const float* ff_b1  = (const float*)d_in[17];
    const float* ff_w2  = (const float*)d_in[18];
    const float* ff_b2  = (const float*)d_in[19];
    float* outp = (float*)d_out;

    // Workspace map (floats, total 2*BHL = 128 MiB):
    //   region A [0, BHL):         u fp32 -> ys4 (scan in place) -> t2T bf16
    //   region B [BHL, 1.5*BHL):   hT bf16 half (B,8192,256)
    //   WP corner [2*BHL-512K floats, ...): bf16 weights (W1c, W2c) + P
    float* wsf  = (float*)d_ws;
    float* u    = wsf;
    u16*   t2T  = (u16*)wsf;
    u16*   hT   = (u16*)(wsf + BHL);
    constexpr size_t WPOFF = 2 * BHL - 524288;
    u16*   W1c  = (u16*)(wsf + WPOFF);              // 512*256 bf16
    u16*   W2c  = W1c + 131072;                     // 256*512 bf16
    float* P    = wsf + WPOFF + 131072;             // 34,816 floats

    setup_s4_params<<<16, 256, 0, stream>>>(log_dt, A_re, A_im, C_re, C_im, P);
    part_t_kernel<<<8, 256, 0, stream>>>(emb, fc_t_w, fc_t_b, P);
    convert_w_kernel<<<512, 256, 0, stream>>>(ff_w1, W1c, 512 * 256);
    convert_w_kernel<<<512, 256, 0, stream>>>(ff_w2, W2c, 256 * 512);

    // u = TLN1(x) + part_t
    tln_kernel<<<dim3(LL / 64, BB), 256, 0, stream>>>(x, u, n1_m, n1_s, P + OFF_PT);

    // ys4 = gelu(S4_bidir(u) + u*D), in place over u
    scan_fused<<<BB * HH, 256, 0, stream>>>(u, P, Dp, u);

    // res = x + GLU(out_w @ ys4 + out_b)  -> d_out   (fp32: sigmoid-sensitive)
    gemm_glu_kernel<<<dim3(LL / 64, 4, BB), 256, 0, stream>>>(u, out_w, out_b, x, outp);

    // t2T = TLN2(res) transposed bf16
    tln2t_kernel<<<dim3(LL / 64, BB), 256, 0, stream>>>(outp, t2T, n2_m, n2_s);

    // FF in two hidden halves; hT half = 32 MB in region B
    gemm_mfma<1, 256><<<dim3(LL / 128, 2, BB), 256, 0, stream>>>(W1c, t2T, ff_b1, nullptr, hT);
    gemm_mfma<2, 512><<<dim3(LL / 128, 2, BB), 256, 0, stream>>>(W2c, hT, ff_b2, outp, outp);
    gemm_mfma<1, 256><<<dim3(LL / 128, 2, BB), 256, 0, stream>>>(W1c + 65536, t2T, ff_b1 + 256, nullptr, hT);
    gemm_mfma<2, 512><<<dim3(LL / 128, 2, BB), 256, 0, stream>>>(W2c + 256, hT, nullptr, outp, outp);
}

// Round 2
// 588.162 us; speedup vs baseline: 1.3342x; 1.2161x over previous
//
#include <hip/hip_runtime.h>
#include <hip/hip_bf16.h>
#include <math.h>

typedef unsigned short u16;
typedef float fx4 __attribute__((ext_vector_type(4)));
typedef __bf16 bx8 __attribute__((ext_vector_type(8)));

constexpr int BB  = 8;
constexpr int HH  = 256;
constexpr int LL  = 8192;
constexpr int NN  = 16;
constexpr int DTE = 512;
constexpr int SC  = 64;     // chunk length for the scan (W^SC used in phase 3)
constexpr int CHN = 128;    // number of chunks per row
constexpr int HN  = HH * NN;

constexpr size_t BHL = (size_t)BB * HH * LL;

constexpr int OFF_WR  = 0;
constexpr int OFF_WI  = HN;
constexpr int OFF_WSR = 2 * HN;
constexpr int OFF_WSI = 3 * HN;
constexpr int OFF_C0R = 4 * HN;
constexpr int OFF_C0I = 5 * HN;
constexpr int OFF_C1R = 6 * HN;
constexpr int OFF_C1I = 7 * HN;
constexpr int OFF_PT  = 8 * HN;

__device__ __forceinline__ float gelu_tanh(float x) {
    float x3 = x * x * x;
    float y = 1.5957691216057308f * x + 0.07135481627767453f * x3;
    return x / (1.0f + __expf(-y));
}
__device__ __forceinline__ float sigmoid_(float x) {
    return 1.0f / (1.0f + __expf(-x));
}
__device__ __forceinline__ __hip_bfloat16 f2b(float x) { return __float2bfloat16(x); }
__device__ __forceinline__ float b2f(__hip_bfloat16 x) { return __bfloat162float(x); }
__device__ __forceinline__ u16 f2us(float x) {
    __hip_bfloat16 b = __float2bfloat16(x);
    return *reinterpret_cast<u16*>(&b);
}
__device__ __forceinline__ float lo2f(unsigned v) { return __uint_as_float(v << 16); }
__device__ __forceinline__ float hi2f(unsigned v) { return __uint_as_float(v & 0xffff0000u); }
__device__ __forceinline__ unsigned pack2(float a, float b) {
    return (unsigned)f2us(a) | ((unsigned)f2us(b) << 16);
}

__global__ void setup_s4_params(const float* __restrict__ log_dt,
                                const float* __restrict__ A_re,
                                const float* __restrict__ A_im,
                                const float* __restrict__ C_re,
                                const float* __restrict__ C_im,
                                float* __restrict__ P) {
    int idx = blockIdx.x * blockDim.x + threadIdx.x;
    if (idx >= HN) return;
    int h = idx >> 4;
    double dt = exp((double)log_dt[h]);
    double Ar = (double)A_re[idx], Ai = (double)A_im[idx];
    double dr = Ar * dt, di = Ai * dt;
    double e1 = exp(dr);
    double wr = e1 * cos(di), wi = e1 * sin(di);
    double eS = exp(dr * SC);
    double wSr = eS * cos(di * SC), wSi = eS * sin(di * SC);
    double d2 = Ar * Ar + Ai * Ai;
    double nr = wr - 1.0, ni = wi;
    double rr = (nr * Ar + ni * Ai) / d2;
    double ri = (ni * Ar - nr * Ai) / d2;
    double c0r = (double)C_re[idx],        c0i = (double)C_im[idx];
    double c1r = (double)C_re[HN + idx],   c1i = (double)C_im[HN + idx];
    P[OFF_WR  + idx] = (float)wr;
    P[OFF_WI  + idx] = (float)wi;
    P[OFF_WSR + idx] = (float)wSr;
    P[OFF_WSI + idx] = (float)wSi;
    P[OFF_C0R + idx] = (float)(2.0 * (c0r * rr - c0i * ri));
    P[OFF_C0I + idx] = (float)(2.0 * (c0r * ri + c0i * rr));
    P[OFF_C1R + idx] = (float)(2.0 * (c1r * rr - c1i * ri));
    P[OFF_C1I + idx] = (float)(2.0 * (c1r * ri + c1i * rr));
}

__global__ void part_t_kernel(const float* __restrict__ emb,
                              const float* __restrict__ w,
                              const float* __restrict__ bias,
                              float* __restrict__ P) {
    int idx = blockIdx.x * blockDim.x + threadIdx.x;
    if (idx >= BB * HH) return;
    int b = idx / HH, h = idx % HH;
    float s = bias[h];
    const float* er = emb + (size_t)b * DTE;
    const float* wr = w + (size_t)h * DTE;
    for (int e = 0; e < DTE; ++e) s = fmaf(er[e], wr[e], s);
    P[OFF_PT + idx] = s;
}

__global__ void convert_w_kernel(const float* __restrict__ src, u16* __restrict__ dst, int n) {
    int i = blockIdx.x * 256 + threadIdx.x;
    if (i < n) dst[i] = f2us(src[i]);
}

// split fp32 -> bf16 hi + bf16 lo (residual)
__global__ void convert_w_split(const float* __restrict__ src,
                                u16* __restrict__ hi, u16* __restrict__ lo, int n) {
    int i = blockIdx.x * 256 + threadIdx.x;
    if (i < n) {
        float v = src[i];
        __hip_bfloat16 hb = f2b(v);
        hi[i] = *reinterpret_cast<u16*>(&hb);
        lo[i] = f2us(v - b2f(hb));
    }
}

__global__ void tln_kernel(const float* __restrict__ in, float* __restrict__ out,
                           const float* __restrict__ mptr, const float* __restrict__ sptr,
                           const float* __restrict__ part_t) {
    int b = blockIdx.y;
    int l0 = blockIdx.x * 64;
    int t = threadIdx.x;
    int q = t >> 6, li = t & 63;
    const float* base = in + (size_t)b * HH * LL + l0 + li;
    float sum = 0.f, sq = 0.f;
    for (int i = 0; i < 64; ++i) {
        float v = base[(size_t)(q * 64 + i) * LL];
        sum += v; sq = fmaf(v, v, sq);
    }
    __shared__ float rs[4][64], rq[4][64], meanS[64], scaleS[64];
    rs[q][li] = sum; rq[q][li] = sq;
    __syncthreads();
    if (q == 0) {
        float s  = rs[0][li] + rs[1][li] + rs[2][li] + rs[3][li];
        float s2 = rq[0][li] + rq[1][li] + rq[2][li] + rq[3][li];
        float mean = s * (1.f / 256.f);
        float var  = fmaxf(s2 * (1.f / 256.f) - mean * mean, 0.f);
        meanS[li]  = mean;
        scaleS[li] = sptr[0] / sqrtf(var);
    }
    __syncthreads();
    float mean = meanS[li], scale = scaleS[li], m = mptr[0];
    float* ob = out + (size_t)b * HH * LL + l0 + li;
    for (int i = 0; i < 64; ++i) {
        int h = q * 64 + i;
        float v = base[(size_t)h * LL];
        float y = scale * (v - mean + m) + part_t[b * HH + h];
        ob[(size_t)h * LL] = y;
    }
}

__global__ void tln2t_kernel(const float* __restrict__ in, u16* __restrict__ outT,
                             const float* __restrict__ mptr, const float* __restrict__ sptr) {
    int b = blockIdx.y;
    int l0 = blockIdx.x * 64;
    int t = threadIdx.x;
    int q = t >> 6, li = t & 63;
    const float* base = in + (size_t)b * HH * LL + l0 + li;
    float sum = 0.f, sq = 0.f;
    for (int i = 0; i < 64; ++i) {
        float v = base[(size_t)(q * 64 + i) * LL];
        sum += v; sq = fmaf(v, v, sq);
    }
    __shared__ float rs[4][64], rq[4][64], meanS[64], scaleS[64];
    __shared__ u16 TT[64 * 262];
    rs[q][li] = sum; rq[q][li] = sq;
    __syncthreads();
    if (q == 0) {
        float s  = rs[0][li] + rs[1][li] + rs[2][li] + rs[3][li];
        float s2 = rq[0][li] + rq[1][li] + rq[2][li] + rq[3][li];
        float mean = s * (1.f / 256.f);
        float var  = fmaxf(s2 * (1.f / 256.f) - mean * mean, 0.f);
        meanS[li]  = mean;
        scaleS[li] = sptr[0] / sqrtf(var);
    }
    __syncthreads();
    float mean = meanS[li], scale = scaleS[li], m = mptr[0];
    for (int i = 0; i < 64; ++i) {
        int h = q * 64 + i;
        float v = base[(size_t)h * LL];
        TT[li * 262 + h] = f2us(scale * (v - mean + m));
    }
    __syncthreads();
    #pragma unroll
    for (int i = 0; i < 32; ++i) {
        int idx = t + i * 256;
        int c = idx & 127, l = idx >> 7;
        unsigned int v = *(const unsigned int*)&TT[l * 262 + 2 * c];
        *(unsigned int*)&outT[((size_t)b * LL + l0 + l) * 256 + 2 * c] = v;
    }
}

// ---- scan: 128 chunks x 64 elements per (b,h) row.
constexpr int SUP  = 65;    // floats per chunk row (odd -> conflict-free column reads)
constexpr int FINP = 258;   // bf16 per fin row: 2*128 + 2 pad

__global__ __launch_bounds__(256, 3) void scan_fused(
    const float* __restrict__ uIn, const float* __restrict__ P,
    const float* __restrict__ Dp, float* __restrict__ ys)
{
    __shared__ __align__(16) float          su[CHN * SUP];     // 33280 B
    __shared__ __align__(16) __hip_bfloat16 ybuf[CHN * SUP];   // 16640 B
    __hip_bfloat16* fin = ybuf;

    const int bh  = blockIdx.x;
    const int h   = bh & (HH - 1);
    const int tid = threadIdx.x;
    const float* urow = uIn + (size_t)bh * LL;
    float* yrow = ys + (size_t)bh * LL;

    {
        const float4* u4 = (const float4*)urow;
        #pragma unroll
        for (int i = 0; i < 8; ++i) {
            int e4 = tid + i * 256;
            float4 v = u4[e4];
            int g = e4 << 2;
            int cc = g >> 6, j = g & 63;
            float* p = &su[cc * SUP + j];
            p[0] = v.x; p[1] = v.y; p[2] = v.z; p[3] = v.w;
        }
    }

    const int c   = tid & 127;
    const int dir = tid >> 7;

    float wr[NN], wi[NN];
    #pragma unroll
    for (int n = 0; n < NN; ++n) {
        wr[n] = P[OFF_WR + h * NN + n];
        wi[n] = P[OFF_WI + h * NN + n];
    }
    __syncthreads();

    {
        float fr[NN], fi[NN];
        #pragma unroll
        for (int n = 0; n < NN; ++n) { fr[n] = 0.f; fi[n] = 0.f; }
        const float* scp = &su[c * SUP];
        if (dir == 0) {
            for (int j = 0; j < 64; ++j) {
                float uv = scp[j];
                #pragma unroll
                for (int n = 0; n < NN; ++n) {
                    float nr = fmaf(wr[n], fr[n], fmaf(-wi[n], fi[n], uv));
                    float ni = fmaf(wr[n], fi[n], wi[n] * fr[n]);
                    fr[n] = nr; fi[n] = ni;
                }
            }
        } else {
            for (int j = 63; j >= 0; --j) {
                float uv = scp[j];
                #pragma unroll
                for (int n = 0; n < NN; ++n) {
                    float nr = fmaf(wr[n], fr[n], fmaf(-wi[n], fi[n], uv));
                    float ni = fmaf(wr[n], fi[n], wi[n] * fr[n]);
                    fr[n] = nr; fi[n] = ni;
                }
            }
        }
        #pragma unroll
        for (int n = 0; n < NN; ++n)
            *(unsigned*)&fin[(dir * NN + n) * FINP + 2 * c] = pack2(fr[n], fi[n]);
    }
    __syncthreads();

    if (tid < 32) {
        const int d3 = tid >> 4, n = tid & 15;
        float wSr = P[OFF_WSR + h * NN + n], wSi = P[OFF_WSI + h * NN + n];
        __hip_bfloat16* fb = &fin[(d3 * NN + n) * FINP];
        float cr = 0.f, ci = 0.f;
        if (d3 == 0) {
            for (int q = 0; q < CHN; ++q) {
                unsigned pv = *(unsigned*)&fb[2 * q];
                float fr = lo2f(pv), fi = hi2f(pv);
                *(unsigned*)&fb[2 * q] = pack2(cr, ci);
                float nr2 = fmaf(wSr, cr, fmaf(-wSi, ci, fr));
                float ni2 = fmaf(wSr, ci, fmaf(wSi, cr, fi));
                cr = nr2; ci = ni2;
            }
        } else {
            for (int q = CHN - 1; q >= 0; --q) {
                unsigned pv = *(unsigned*)&fb[2 * q];
                float fr = lo2f(pv), fi = hi2f(pv);
                *(unsigned*)&fb[2 * q] = pack2(cr, ci);
                float nr2 = fmaf(wSr, cr, fmaf(-wSi, ci, fr));
                float ni2 = fmaf(wSr, ci, fmaf(wSi, cr, fi));
                cr = nr2; ci = ni2;
            }
        }
    }
    __syncthreads();

    float cr16[NN], ci16[NN], sr[NN], si[NN];
    {
        const int cO = dir ? OFF_C1R : OFF_C0R;
        const int cI = dir ? OFF_C1I : OFF_C0I;
        #pragma unroll
        for (int n = 0; n < NN; ++n) {
            cr16[n] = P[cO + h * NN + n];
            ci16[n] = P[cI + h * NN + n];
            unsigned pv = *(const unsigned*)&fin[(dir * NN + n) * FINP + 2 * c];
            sr[n] = lo2f(pv); si[n] = hi2f(pv);
        }
    }
    __syncthreads();

    float* sc = &su[c * SUP];
    __hip_bfloat16* yc = &ybuf[c * SUP];
    const float Dh = Dp[h];
    float ucur = 0.f;

    if (dir == 0) {
        for (int j = 0; j < 32; ++j) {
            float uv = sc[j];
            float acc = 0.f;
            #pragma unroll
            for (int n = 0; n < NN; ++n) {
                float nr = fmaf(wr[n], sr[n], fmaf(-wi[n], si[n], uv));
                float ni = fmaf(wr[n], si[n], wi[n] * sr[n]);
                sr[n] = nr; si[n] = ni;
                acc = fmaf(cr16[n], nr, fmaf(-ci16[n], ni, acc));
            }
            yc[j] = f2b(acc);
        }
    } else {
        {
            float acc = 0.f;
            #pragma unroll
            for (int n = 0; n < NN; ++n)
                acc = fmaf(cr16[n], sr[n], fmaf(-ci16[n], si[n], acc));
            yc[63] = f2b(acc);
        }
        for (int t = 63; t >= 33; --t) {
            float uv = sc[t];
            float acc = 0.f;
            #pragma unroll
            for (int n = 0; n < NN; ++n) {
                float nr = fmaf(wr[n], sr[n], fmaf(-wi[n], si[n], uv));
                float ni = fmaf(wr[n], si[n], wi[n] * sr[n]);
                sr[n] = nr; si[n] = ni;
                acc = fmaf(cr16[n], nr, fmaf(-ci16[n], ni, acc));
            }
            yc[t - 1] = f2b(acc);
        }
        ucur = sc[32];
    }
    __syncthreads();

    if (dir == 0) {
        for (int j = 32; j < 64; ++j) {
            float uv = sc[j];
            float acc = 0.f;
            #pragma unroll
            for (int n = 0; n < NN; ++n) {
                float nr = fmaf(wr[n], sr[n], fmaf(-wi[n], si[n], uv));
                float ni = fmaf(wr[n], si[n], wi[n] * sr[n]);
                sr[n] = nr; si[n] = ni;
                acc = fmaf(cr16[n], nr, fmaf(-ci16[n], ni, acc));
            }
            float tot = acc + b2f(yc[j]) + uv * Dh;
            sc[j] = gelu_tanh(tot);
        }
    } else {
        for (int t = 32; t >= 1; --t) {
            float acc = 0.f;
            #pragma unroll
            for (int n = 0; n < NN; ++n) {
                float nr = fmaf(wr[n], sr[n], fmaf(-wi[n], si[n], ucur));
                float ni = fmaf(wr[n], si[n], wi[n] * sr[n]);
                sr[n] = nr; si[n] = ni;
                acc = fmaf(cr16[n], nr, fmaf(-ci16[n], ni, acc));
            }
            float un = sc[t - 1];
            float tot = acc + b2f(yc[t - 1]) + un * Dh;
            sc[t - 1] = gelu_tanh(tot);
            ucur = un;
        }
    }
    __syncthreads();

    {
        #pragma unroll
        for (int i = 0; i < 8; ++i) {
            int e4 = tid + i * 256;
            int g = e4 << 2;
            int c2 = g >> 6, j = g & 63;
            const float* p = &su[c2 * SUP + j];
            float4 v;
            v.x = p[0]; v.y = p[1]; v.z = p[2]; v.w = p[3];
            ((float4*)yrow)[e4] = v;
        }
    }
}

// ---- GLU output projection via split-bf16 MFMA.
// z = out_w @ y (K=256); block computes 64 GLU channels x 128 l.
// A-tile = 128 rows: [c0..c0+64) (z0) ++ [c0+256..c0+320) (z1).
// Split precision: z ~= Wh*Yh + Wh*Yl + Wl*Yh  (error ~2^-18 relative).
__global__ __launch_bounds__(256, 2) void gemm_glu_mfma(
    const u16* __restrict__ Whi, const u16* __restrict__ Wlo,
    const float* __restrict__ Y, const float* __restrict__ bias,
    const float* __restrict__ xres, float* __restrict__ out)
{
    __shared__ __align__(16) char smem[65536];
    u16* Ah = (u16*)smem;                 // [2ks][8mt][64lane][8] = 16 KiB
    u16* Al = Ah + 8192;
    u16* Bh = Al + 8192;
    u16* Bl = Bh + 8192;

    const int tid  = threadIdx.x;
    const int lane = tid & 63;
    const int wv   = tid >> 6;
    const int wrh  = wv & 1;      // m-half: 0 -> z0 rows, 1 -> z1 rows
    const int wch  = wv >> 1;     // n-half: l offset wch*64
    const int bz   = blockIdx.z;
    const int l0   = blockIdx.x * 128;
    const int c0   = blockIdx.y * 64;

    fx4 acc[4][4];
    #pragma unroll
    for (int i = 0; i < 4; ++i)
        #pragma unroll
        for (int j = 0; j < 4; ++j) {
            fx4 z = {0.f, 0.f, 0.f, 0.f};
            acc[i][j] = z;
        }

    // staging thread maps
    const int am  = tid & 127;            // A: m row 0..127
    const int akh = tid >> 7;             // A: k half (ks)
    const int aorow = (am < 64) ? (c0 + am) : (c0 + 256 + (am - 64));
    const int amt = am >> 4, amm = am & 15;

    const int bli = (tid & 63) + ((tid >> 6) & 1) * 64;   // B: l 0..127
    const int bkh = tid >> 7;                              // B: k half (ks)
    const int bnt = bli >> 4, bcol = bli & 15;

    const float* Yb = Y + (size_t)bz * HH * LL + l0;

    for (int k0 = 0; k0 < 256; k0 += 64) {
        // stage A (pre-split bf16 weights, frag-ordered)
        #pragma unroll
        for (int oct = 0; oct < 4; ++oct) {
            int k = k0 + akh * 32 + oct * 8;
            int4 vh = *(const int4*)&Whi[(size_t)aorow * 256 + k];
            int4 vl = *(const int4*)&Wlo[(size_t)aorow * 256 + k];
            int base = ((akh * 8 + amt) * 64 + amm + (oct << 4)) * 8;
            *(int4*)&Ah[base] = vh;
            *(int4*)&Al[base] = vl;
        }
        // stage B: gather 8 k-contiguous fp32 per octet (per-lane column of Y),
        // split to hi/lo bf16, write frag-ordered b128
        #pragma unroll
        for (int oct = 0; oct < 4; ++oct) {
            int kb = k0 + bkh * 32 + oct * 8;
            float v[8];
            #pragma unroll
            for (int j = 0; j < 8; ++j)
                v[j] = Yb[(size_t)(kb + j) * LL + bli];
            u16 h8[8], l8[8];
            #pragma unroll
            for (int j = 0; j < 8; ++j) {
                __hip_bfloat16 hb = f2b(v[j]);
                h8[j] = *reinterpret_cast<u16*>(&hb);
                l8[j] = f2us(v[j] - b2f(hb));
            }
            int base = ((bkh * 8 + bnt) * 64 + bcol + (oct << 4)) * 8;
            *(int4*)&Bh[base] = *(const int4*)h8;
            *(int4*)&Bl[base] = *(const int4*)l8;
        }
        __syncthreads();
        #pragma unroll
        for (int ks = 0; ks < 2; ++ks) {
            bx8 bh[4], bl[4];
            #pragma unroll
            for (int nt = 0; nt < 4; ++nt) {
                int base = ((ks * 8 + wch * 4 + nt) * 64 + lane) * 8;
                bh[nt] = *(const bx8*)&Bh[base];
                bl[nt] = *(const bx8*)&Bl[base];
            }
            #pragma unroll
            for (int mt = 0; mt < 4; ++mt) {
                int base = ((ks * 8 + wrh * 4 + mt) * 64 + lane) * 8;
                bx8 ah = *(const bx8*)&Ah[base];
                bx8 al = *(const bx8*)&Al[base];
                #pragma unroll
                for (int nt = 0; nt < 4; ++nt) {
                    acc[mt][nt] = __builtin_amdgcn_mfma_f32_16x16x32_bf16(ah, bh[nt], acc[mt][nt], 0, 0, 0);
                    acc[mt][nt] = __builtin_amdgcn_mfma_f32_16x16x32_bf16(ah, bl[nt], acc[mt][nt], 0, 0, 0);
                    acc[mt][nt] = __builtin_amdgcn_mfma_f32_16x16x32_bf16(al, bh[nt], acc[mt][nt], 0, 0, 0);
                }
            }
        }
        __syncthreads();
    }

    // epilogue: z1 waves publish to LDS, z0 waves apply GLU + residual
    float* zbuf = (float*)smem;   // [2 n-halves][64 m][65] = 33280 B (aliases A/B)
    const int frow = (lane >> 4) * 2 * 2;   // (lane>>4)*4
    if (wrh == 1) {
        #pragma unroll
        for (int mt = 0; mt < 4; ++mt) {
            int mloc = mt * 16 + (lane >> 4) * 4;
            float b1v[4];
            #pragma unroll
            for (int r = 0; r < 4; ++r) b1v[r] = bias[c0 + 256 + mloc + r];
            #pragma unroll
            for (int nt = 0; nt < 4; ++nt) {
                int nloc = nt * 16 + (lane & 15);
                #pragma unroll
                for (int r = 0; r < 4; ++r)
                    zbuf[wch * 4160 + (mloc + r) * 65 + nloc] = acc[mt][nt][r] + b1v[r];
            }
        }
    }
    __syncthreads();
    if (wrh == 0) {
        #pragma unroll
        for (int mt = 0; mt < 4; ++mt) {
            int mloc = mt * 16 + (lane >> 4) * 4;
            float b0v[4];
            #pragma unroll
            for (int r = 0; r < 4; ++r) b0v[r] = bias[c0 + mloc + r];
            #pragma unroll
            for (int nt = 0; nt < 4; ++nt) {
                int nloc = nt * 16 + (lane & 15);
                int l = l0 + wch * 64 + nloc;
                #pragma unroll
                for (int r = 0; r < 4; ++r) {
                    float z1 = zbuf[wch * 4160 + (mloc + r) * 65 + nloc];
                    float z0 = acc[mt][nt][r] + b0v[r];
                    size_t ga = ((size_t)bz * HH + c0 + mloc + r) * LL + l;
                    out[ga] = z0 * sigmoid_(z1) + xres[ga];
                }
            }
        }
    }
    (void)frow;
}

template<int MODE, int WLD>
__global__ __launch_bounds__(256, 3) void gemm_mfma(
    const u16* __restrict__ Aw, const u16* __restrict__ Bm,
    const float* bias, const float* resid, void* outv)
{
    __shared__ __align__(16) char smem[33792];
    u16*   Alds = (u16*)smem;
    u16*   Blds = (u16*)(smem + 16384);
    float* Eps  = (float*)smem;
    u16*   TT   = (u16*)smem;

    const int tid  = threadIdx.x;
    const int lane = tid & 63;
    const int wv   = tid >> 6;
    const int wr   = wv >> 1, wc = wv & 1;
    const int bz   = blockIdx.z;
    const int l0   = blockIdx.x * 128;
    const int mbase = blockIdx.y * 128;

    fx4 acc[4][4];
    #pragma unroll
    for (int i = 0; i < 4; ++i)
        #pragma unroll
        for (int j = 0; j < 4; ++j) {
            fx4 z = {0.f, 0.f, 0.f, 0.f};
            acc[i][j] = z;
        }

    const size_t brow0 = (size_t)bz * LL;
    for (int k0 = 0; k0 < 256; k0 += 64) {
        #pragma unroll
        for (int i = 0; i < 4; ++i) {
            int f = tid + i * 256;
            int mm = f & 15, kg = (f >> 4) & 3, m16 = (f >> 6) & 7, ks = f >> 9;
            int k = k0 + ks * 32 + kg * 8;
            int o = mbase + m16 * 16 + mm;
            int4 wv4 = *(const int4*)(Aw + (size_t)o * WLD + k);
            *(int4*)&Alds[f * 8] = wv4;
            int row = l0 + m16 * 16 + mm;
            int4 xv4 = *(const int4*)(Bm + (brow0 + row) * 256 + k);
            *(int4*)&Blds[f * 8] = xv4;
        }
        __syncthreads();
        #pragma unroll
        for (int ks = 0; ks < 2; ++ks) {
            bx8 av[4], bv[4];
            #pragma unroll
            for (int mt = 0; mt < 4; ++mt)
                av[mt] = *(const bx8*)&Alds[(ks * 512 + (wr * 4 + mt) * 64 + lane) * 8];
            #pragma unroll
            for (int nt = 0; nt < 4; ++nt)
                bv[nt] = *(const bx8*)&Blds[(ks * 512 + (wc * 4 + nt) * 64 + lane) * 8];
            #pragma unroll
            for (int mt = 0; mt < 4; ++mt)
                #pragma unroll
                for (int nt = 0; nt < 4; ++nt)
                    acc[mt][nt] = __builtin_amdgcn_mfma_f32_16x16x32_bf16(
                        av[mt], bv[nt], acc[mt][nt], 0, 0, 0);
        }
        __syncthreads();
    }

    if (MODE == 1) {
        u16* hT = (u16*)outv;
        #pragma unroll
        for (int p = 0; p < 2; ++p) {
            if (p) __syncthreads();
            if (wc == p) {
                #pragma unroll
                for (int mt = 0; mt < 4; ++mt) {
                    int mb = wr * 64 + mt * 16 + (lane >> 4) * 4;
                    float bvv[4];
                    #pragma unroll
                    for (int r = 0; r < 4; ++r) bvv[r] = bias[mbase + mb + r];
                    #pragma unroll
                    for (int nt = 0; nt < 4; ++nt) {
                        int n = nt * 16 + (lane & 15);
                        u16 pk[4];
                        #pragma unroll
                        for (int r = 0; r < 4; ++r)
                            pk[r] = f2us(gelu_tanh(acc[mt][nt][r] + bvv[r]));
                        *(ushort4*)&TT[n * 136 + mb] = *(const ushort4*)pk;
                    }
                }
            }
            __syncthreads();
            #pragma unroll
            for (int i = 0; i < 4; ++i) {
                int idx = tid + i * 256;
                int l = idx >> 4, c = idx & 15;
                int4 v = *(const int4*)&TT[l * 136 + c * 8];
                *(int4*)&hT[((size_t)bz * LL + l0 + p * 64 + l) * 256 + mbase + c * 8] = v;
            }
        }
    } else {
        float* outp = (float*)outv;
        #pragma unroll
        for (int p = 0; p < 2; ++p) {
            if (p) __syncthreads();
            if (wc == p) {
                #pragma unroll
                for (int mt = 0; mt < 4; ++mt)
                    #pragma unroll
                    for (int nt = 0; nt < 4; ++nt) {
                        int m = wr * 64 + mt * 16 + (lane >> 4) * 4;
                        int n = nt * 16 + (lane & 15);
                        #pragma unroll
                        for (int r = 0; r < 4; ++r)
                            Eps[(m + r) * 66 + n] = acc[mt][nt][r];
                    }
            }
            __syncthreads();
            #pragma unroll
            for (int i = 0; i < 8; ++i) {
                int idx = tid + i * 256;
                int r = idx >> 4, lq = idx & 15;
                float bv = bias ? bias[mbase + r] : 0.f;
                size_t ga = ((size_t)bz * HH + mbase + r) * LL + l0 + p * 64 + lq * 4;
                float4 rv = *(const float4*)&resid[ga];
                float4 ov;
                #pragma unroll
                for (int j = 0; j < 4; ++j)
                    (&ov.x)[j] = Eps[r * 66 + lq * 4 + j] + bv + (&rv.x)[j];
                *(float4*)&outp[ga] = ov;
            }
        }
    }
}

extern "C" void kernel_launch(void* const* d_in, const int* in_sizes, int n_in,
                              void* d_out, int out_size, void* d_ws, size_t ws_size,
                              hipStream_t stream) {
    (void)in_sizes; (void)n_in; (void)out_size; (void)ws_size;
    const float* x      = (const float*)d_in[0];
    const float* emb    = (const float*)d_in[1];
    const float* fc_t_w = (const float*)d_in[2];
    const float* fc_t_b = (const float*)d_in[3];
    const float* log_dt = (const float*)d_in[4];
    const float* A_re   = (const float*)d_in[5];
    const float* A_im   = (const float*)d_in[6];
    const float* C_re   = (const float*)d_in[7];
    const float* C_im   = (const float*)d_in[8];
    const float* Dp     = (const float*)d_in[9];
    const float* out_w  = (const float*)d_in[10];
    const float* out_b  = (const float*)d_in[11];
    const float* n1_m   = (const float*)d_in[12];
    const float* n1_s   = (const float*)d_in[13];
    const float* n2_m   = (const float*)d_in[14];
    const float* n2_s   = (const float*)d_in[15];
    const float* ff_w1  = (const float*)d_in[16];
    const float* ff_b1  = (const float*)d_in[17];
    const float* ff_w2  = (const float*)d_in[18];
    const float* ff_b2  = (const float*)d_in[19];
    float* outp = (float*)d_out;

    // Workspace map (floats, total 2*BHL = 128 MiB):
    //   region A [0, BHL):         u fp32 -> ys4 (scan in place) -> t2T bf16
    //   region B [BHL, 1.5*BHL):   hT bf16 half (B,8192,256)
    //   WP corner [2*BHL-512K floats, ...): bf16 weights + P
    float* wsf  = (float*)d_ws;
    float* u    = wsf;
    u16*   t2T  = (u16*)wsf;
    u16*   hT   = (u16*)(wsf + BHL);
    constexpr size_t WPOFF = 2 * BHL - 524288;
    u16*   W1c  = (u16*)(wsf + WPOFF);              // 512*256 bf16
    u16*   W2c  = W1c + 131072;                     // 256*512 bf16
    u16*   WOh  = W2c + 131072;                     // out_w hi 512*256 bf16
    u16*   WOl  = WOh + 131072;                     // out_w lo 512*256 bf16
    float* P    = wsf + WPOFF + 262144;             // 34,816 floats

    setup_s4_params<<<16, 256, 0, stream>>>(log_dt, A_re, A_im, C_re, C_im, P);
    part_t_kernel<<<8, 256, 0, stream>>>(emb, fc_t_w, fc_t_b, P);
    convert_w_kernel<<<512, 256, 0, stream>>>(ff_w1, W1c, 512 * 256);
    convert_w_kernel<<<512, 256, 0, stream>>>(ff_w2, W2c, 256 * 512);
    convert_w_split<<<512, 256, 0, stream>>>(out_w, WOh, WOl, 512 * 256);

    // u = TLN1(x) + part_t
    tln_kernel<<<dim3(LL / 64, BB), 256, 0, stream>>>(x, u, n1_m, n1_s, P + OFF_PT);

    // ys4 = gelu(S4_bidir(u) + u*D), in place over u
    scan_fused<<<BB * HH, 256, 0, stream>>>(u, P, Dp, u);

    // res = x + GLU(out_w @ ys4 + out_b) -> d_out   (split-bf16 MFMA, fp32-class accuracy)
    gemm_glu_mfma<<<dim3(LL / 128, 4, BB), 256, 0, stream>>>(WOh, WOl, u, out_b, x, outp);

    // t2T = TLN2(res) transposed bf16
    tln2t_kernel<<<dim3(LL / 64, BB), 256, 0, stream>>>(outp, t2T, n2_m, n2_s);

    // FF in two hidden halves; hT half = 32 MB in region B
    gemm_mfma<1, 256><<<dim3(LL / 128, 2, BB), 256, 0, stream>>>(W1c, t2T, ff_b1, nullptr, hT);
    gemm_mfma<2, 512><<<dim3(LL / 128, 2, BB), 256, 0, stream>>>(W2c, hT, ff_b2, outp, outp);
    gemm_mfma<1, 256><<<dim3(LL / 128, 2, BB), 256, 0, stream>>>(W1c + 65536, t2T, ff_b1 + 256, nullptr, hT);
    gemm_mfma<2, 512><<<dim3(LL / 128, 2, BB), 256, 0, stream>>>(W2c + 256, hT, nullptr, outp, outp);
}

// Round 3
// 537.410 us; speedup vs baseline: 1.4602x; 1.0944x over previous
//
#include <hip/hip_runtime.h>
#include <hip/hip_bf16.h>
#include <math.h>

typedef unsigned short u16;
typedef float fx4 __attribute__((ext_vector_type(4)));
typedef __bf16 bx8 __attribute__((ext_vector_type(8)));

constexpr int BB  = 8;
constexpr int HH  = 256;
constexpr int LL  = 8192;
constexpr int NN  = 16;
constexpr int DTE = 512;
constexpr int SC  = 64;     // chunk length for the scan (W^SC used in carry scan)
constexpr int CHN = 128;    // number of chunks per row
constexpr int HN  = HH * NN;

constexpr size_t BHL = (size_t)BB * HH * LL;

constexpr int OFF_WR  = 0;
constexpr int OFF_WI  = HN;
constexpr int OFF_WSR = 2 * HN;
constexpr int OFF_WSI = 3 * HN;
constexpr int OFF_C0R = 4 * HN;
constexpr int OFF_C0I = 5 * HN;
constexpr int OFF_C1R = 6 * HN;
constexpr int OFF_C1I = 7 * HN;
constexpr int OFF_PT  = 8 * HN;

// PM (per-h scan matrices, u16 units): 6x 64x64 bf16
constexpr int PM_V2H = 0;
constexpr int PM_V2L = 4096;
constexpr int PM_TH  = 8192;
constexpr int PM_TL  = 12288;
constexpr int PM_CWH = 16384;
constexpr int PM_CWL = 20480;
constexpr int PM_STRIDE = 24576;

__device__ __forceinline__ float gelu_tanh(float x) {
    float x3 = x * x * x;
    float y = 1.5957691216057308f * x + 0.07135481627767453f * x3;
    return x / (1.0f + __expf(-y));
}
__device__ __forceinline__ float sigmoid_(float x) {
    return 1.0f / (1.0f + __expf(-x));
}
__device__ __forceinline__ __hip_bfloat16 f2b(float x) { return __float2bfloat16(x); }
__device__ __forceinline__ float b2f(__hip_bfloat16 x) { return __bfloat162float(x); }
__device__ __forceinline__ u16 f2us(float x) {
    __hip_bfloat16 b = __float2bfloat16(x);
    return *reinterpret_cast<u16*>(&b);
}
__device__ __forceinline__ float lo2f(unsigned v) { return __uint_as_float(v << 16); }
__device__ __forceinline__ float hi2f(unsigned v) { return __uint_as_float(v & 0xffff0000u); }
__device__ __forceinline__ unsigned pack2(float a, float b) {
    return (unsigned)f2us(a) | ((unsigned)f2us(b) << 16);
}

__global__ void setup_s4_params(const float* __restrict__ log_dt,
                                const float* __restrict__ A_re,
                                const float* __restrict__ A_im,
                                const float* __restrict__ C_re,
                                const float* __restrict__ C_im,
                                float* __restrict__ P) {
    int idx = blockIdx.x * blockDim.x + threadIdx.x;
    if (idx >= HN) return;
    int h = idx >> 4;
    double dt = exp((double)log_dt[h]);
    double Ar = (double)A_re[idx], Ai = (double)A_im[idx];
    double dr = Ar * dt, di = Ai * dt;
    double e1 = exp(dr);
    double wr = e1 * cos(di), wi = e1 * sin(di);
    double eS = exp(dr * SC);
    double wSr = eS * cos(di * SC), wSi = eS * sin(di * SC);
    double d2 = Ar * Ar + Ai * Ai;
    double nr = wr - 1.0, ni = wi;
    double rr = (nr * Ar + ni * Ai) / d2;
    double ri = (ni * Ar - nr * Ai) / d2;
    double c0r = (double)C_re[idx],        c0i = (double)C_im[idx];
    double c1r = (double)C_re[HN + idx],   c1i = (double)C_im[HN + idx];
    P[OFF_WR  + idx] = (float)wr;
    P[OFF_WI  + idx] = (float)wi;
    P[OFF_WSR + idx] = (float)wSr;
    P[OFF_WSI + idx] = (float)wSi;
    P[OFF_C0R + idx] = (float)(2.0 * (c0r * rr - c0i * ri));
    P[OFF_C0I + idx] = (float)(2.0 * (c0r * ri + c0i * rr));
    P[OFF_C1R + idx] = (float)(2.0 * (c1r * rr - c1i * ri));
    P[OFF_C1I + idx] = (float)(2.0 * (c1r * ri + c1i * rr));
}

// Per-h scan matrices: V2 (states x j), T (t x j Toeplitz, D on diag), CW (t x carry-state).
// One block per h, 64 threads (thread = row t).
__global__ void setup_scan_mats(const float* __restrict__ P,
                                const float* __restrict__ Dp,
                                u16* __restrict__ PM) {
    const int h = blockIdx.x;
    const int t = threadIdx.x;   // 0..63
    __shared__ float Wr[65][17], Wi[65][17];
    __shared__ float KF[64], KB[64];
    __shared__ float c0r[16], c0i[16], c1r[16], c1i[16];
    if (t < 16) {
        c0r[t] = P[OFF_C0R + h * NN + t]; c0i[t] = P[OFF_C0I + h * NN + t];
        c1r[t] = P[OFF_C1R + h * NN + t]; c1i[t] = P[OFF_C1I + h * NN + t];
        double wr = (double)P[OFF_WR + h * NN + t], wi = (double)P[OFF_WI + h * NN + t];
        double pr = 1.0, pi = 0.0;
        for (int tau = 0; tau <= 64; ++tau) {
            Wr[tau][t] = (float)pr; Wi[tau][t] = (float)pi;
            double nr = pr * wr - pi * wi, ni = pr * wi + pi * wr;
            pr = nr; pi = ni;
        }
    }
    __syncthreads();
    {
        float kf = 0.f, kb = 0.f;
        #pragma unroll
        for (int n = 0; n < 16; ++n) {
            kf = fmaf(c0r[n], Wr[t][n], fmaf(-c0i[n], Wi[t][n], kf));
            kb = fmaf(c1r[n], Wr[t][n], fmaf(-c1i[n], Wi[t][n], kb));
        }
        KF[t] = kf; KB[t] = kb;
    }
    __syncthreads();
    u16* base = PM + (size_t)h * PM_STRIDE;
    // V2 row t: rows 0..31 fwd (2n=Re,2n+1=Im of w^{63-j}); 32..63 bwd (w^j)
    {
        int n = (t & 31) >> 1, reim = t & 1;
        bool fwd = t < 32;
        for (int j = 0; j < 64; ++j) {
            int e = fwd ? (63 - j) : j;
            float v = reim ? Wi[e][n] : Wr[e][n];
            __hip_bfloat16 hb = f2b(v);
            base[PM_V2H + t * 64 + j] = *(u16*)&hb;
            base[PM_V2L + t * 64 + j] = f2us(v - b2f(hb));
        }
    }
    // T row t: j<t: KF[t-j]; j==t: KF[0]+D; j>t: KB[j-t-1]
    {
        float Dh = Dp[h];
        for (int j = 0; j < 64; ++j) {
            float v = (j < t) ? KF[t - j] : ((j == t) ? (KF[0] + Dh) : KB[j - t - 1]);
            __hip_bfloat16 hb = f2b(v);
            base[PM_TH + t * 64 + j] = *(u16*)&hb;
            base[PM_TL + t * 64 + j] = f2us(v - b2f(hb));
        }
    }
    // CW row t: cols 2n/2n+1 fwd via w^{t+1}, cols 32+2n/+1 bwd via w^{63-t}
    {
        #pragma unroll
        for (int n = 0; n < 16; ++n) {
            float Rw = Wr[t + 1][n], Iw = Wi[t + 1][n];
            float af = fmaf(c0r[n], Rw, -c0i[n] * Iw);
            float bf = -fmaf(c0r[n], Iw, c0i[n] * Rw);
            float Rb = Wr[63 - t][n], Ib = Wi[63 - t][n];
            float ab = fmaf(c1r[n], Rb, -c1i[n] * Ib);
            float bb = -fmaf(c1r[n], Ib, c1i[n] * Rb);
            float vals[4] = {af, bf, ab, bb};
            int cols[4] = {2 * n, 2 * n + 1, 32 + 2 * n, 32 + 2 * n + 1};
            #pragma unroll
            for (int q = 0; q < 4; ++q) {
                __hip_bfloat16 hb = f2b(vals[q]);
                base[PM_CWH + t * 64 + cols[q]] = *(u16*)&hb;
                base[PM_CWL + t * 64 + cols[q]] = f2us(vals[q] - b2f(hb));
            }
        }
    }
}

__global__ void part_t_kernel(const float* __restrict__ emb,
                              const float* __restrict__ w,
                              const float* __restrict__ bias,
                              float* __restrict__ P) {
    int idx = blockIdx.x * blockDim.x + threadIdx.x;
    if (idx >= BB * HH) return;
    int b = idx / HH, h = idx % HH;
    float s = bias[h];
    const float* er = emb + (size_t)b * DTE;
    const float* wr = w + (size_t)h * DTE;
    for (int e = 0; e < DTE; ++e) s = fmaf(er[e], wr[e], s);
    P[OFF_PT + idx] = s;
}

__global__ void convert_w_kernel(const float* __restrict__ src, u16* __restrict__ dst, int n) {
    int i = blockIdx.x * 256 + threadIdx.x;
    if (i < n) dst[i] = f2us(src[i]);
}

__global__ void convert_w_split(const float* __restrict__ src,
                                u16* __restrict__ hi, u16* __restrict__ lo, int n) {
    int i = blockIdx.x * 256 + threadIdx.x;
    if (i < n) {
        float v = src[i];
        __hip_bfloat16 hb = f2b(v);
        hi[i] = *reinterpret_cast<u16*>(&hb);
        lo[i] = f2us(v - b2f(hb));
    }
}

__global__ void tln_kernel(const float* __restrict__ in, float* __restrict__ out,
                           const float* __restrict__ mptr, const float* __restrict__ sptr,
                           const float* __restrict__ part_t) {
    int b = blockIdx.y;
    int l0 = blockIdx.x * 64;
    int t = threadIdx.x;
    int q = t >> 6, li = t & 63;
    const float* base = in + (size_t)b * HH * LL + l0 + li;
    float sum = 0.f, sq = 0.f;
    for (int i = 0; i < 64; ++i) {
        float v = base[(size_t)(q * 64 + i) * LL];
        sum += v; sq = fmaf(v, v, sq);
    }
    __shared__ float rs[4][64], rq[4][64], meanS[64], scaleS[64];
    rs[q][li] = sum; rq[q][li] = sq;
    __syncthreads();
    if (q == 0) {
        float s  = rs[0][li] + rs[1][li] + rs[2][li] + rs[3][li];
        float s2 = rq[0][li] + rq[1][li] + rq[2][li] + rq[3][li];
        float mean = s * (1.f / 256.f);
        float var  = fmaxf(s2 * (1.f / 256.f) - mean * mean, 0.f);
        meanS[li]  = mean;
        scaleS[li] = sptr[0] / sqrtf(var);
    }
    __syncthreads();
    float mean = meanS[li], scale = scaleS[li], m = mptr[0];
    float* ob = out + (size_t)b * HH * LL + l0 + li;
    for (int i = 0; i < 64; ++i) {
        int h = q * 64 + i;
        float v = base[(size_t)h * LL];
        float y = scale * (v - mean + m) + part_t[b * HH + h];
        ob[(size_t)h * LL] = y;
    }
}

__global__ void tln2t_kernel(const float* __restrict__ in, u16* __restrict__ outT,
                             const float* __restrict__ mptr, const float* __restrict__ sptr) {
    int b = blockIdx.y;
    int l0 = blockIdx.x * 64;
    int t = threadIdx.x;
    int q = t >> 6, li = t & 63;
    const float* base = in + (size_t)b * HH * LL + l0 + li;
    float sum = 0.f, sq = 0.f;
    for (int i = 0; i < 64; ++i) {
        float v = base[(size_t)(q * 64 + i) * LL];
        sum += v; sq = fmaf(v, v, sq);
    }
    __shared__ float rs[4][64], rq[4][64], meanS[64], scaleS[64];
    __shared__ u16 TT[64 * 262];
    rs[q][li] = sum; rq[q][li] = sq;
    __syncthreads();
    if (q == 0) {
        float s  = rs[0][li] + rs[1][li] + rs[2][li] + rs[3][li];
        float s2 = rq[0][li] + rq[1][li] + rq[2][li] + rq[3][li];
        float mean = s * (1.f / 256.f);
        float var  = fmaxf(s2 * (1.f / 256.f) - mean * mean, 0.f);
        meanS[li]  = mean;
        scaleS[li] = sptr[0] / sqrtf(var);
    }
    __syncthreads();
    float mean = meanS[li], scale = scaleS[li], m = mptr[0];
    for (int i = 0; i < 64; ++i) {
        int h = q * 64 + i;
        float v = base[(size_t)h * LL];
        TT[li * 262 + h] = f2us(scale * (v - mean + m));
    }
    __syncthreads();
    #pragma unroll
    for (int i = 0; i < 32; ++i) {
        int idx = t + i * 256;
        int c = idx & 127, l = idx >> 7;
        unsigned int v = *(const unsigned int*)&TT[l * 262 + 2 * c];
        *(unsigned int*)&outT[((size_t)b * LL + l0 + l) * 256 + 2 * c] = v;
    }
}

// ---- MFMA scan: per (b,h) row, chunks of 64.
// SE = V2 @ U  (chunk end states, both dirs stacked: rows 0..31 fwd re/im, 32..63 bwd)
// serial carry scan over 128 chunks (32 threads)
// Y = T @ U + CW @ S0, then gelu.
// U split hi/lo bf16; SE/S0 plain bf16 (same quantization as verified scan_fused).
constexpr int UPAD = 136;   // u16 per chunk row: [hi 64 | lo 64 | pad 8]; 272B (odd 16B groups)
constexpr int SPAD = 72;    // SES row stride u16: 144B (odd 16B groups)

__global__ __launch_bounds__(256, 3) void scan_mfma(
    const float* __restrict__ uIn, const float* __restrict__ P,
    const u16* __restrict__ PM, float* __restrict__ ys)
{
    __shared__ __align__(16) u16 U[128 * UPAD];    // 34816 B
    __shared__ __align__(16) u16 SES[128 * SPAD];  // 18432 B

    const int bh  = blockIdx.x;
    const int h   = bh & (HH - 1);
    const int tid = threadIdx.x;
    const int lane = tid & 63;
    const int wq   = tid >> 6;          // wave's chunk-quarter (32 chunks)
    const u16* pm = PM + (size_t)h * PM_STRIDE;
    const float* urow = uIn + (size_t)bh * LL;
    float* yrow = ys + (size_t)bh * LL;

    // stage u -> split bf16 LDS
    {
        const float4* u4 = (const float4*)urow;
        #pragma unroll
        for (int i = 0; i < 8; ++i) {
            int e4 = tid + i * 256;
            float4 v = u4[e4];
            int g = e4 << 2, c = g >> 6, j = g & 63;
            u16 hi4[4], lo4[4];
            #pragma unroll
            for (int q = 0; q < 4; ++q) {
                float f = (&v.x)[q];
                __hip_bfloat16 hb = f2b(f);
                hi4[q] = *(u16*)&hb;
                lo4[q] = f2us(f - b2f(hb));
            }
            *(ushort4*)&U[c * UPAD + j]      = *(ushort4*)hi4;
            *(ushort4*)&U[c * UPAD + 64 + j] = *(ushort4*)lo4;
        }
    }
    __syncthreads();

    const int cb    = wq * 32 + (lane & 15);      // chunk col base (nt adds 16)
    const int kfrag = ((lane >> 4) & 3) * 8;      // k-octet within 32
    const int arow_lo = lane & 15;                // A-fragment row within tile

    // U fragments (reused by M1 and M2a)
    bx8 ubh[2][2], ubl[2][2];
    #pragma unroll
    for (int nt = 0; nt < 2; ++nt) {
        int c = cb + nt * 16;
        #pragma unroll
        for (int ks = 0; ks < 2; ++ks) {
            ubh[nt][ks] = *(const bx8*)&U[c * UPAD + ks * 32 + kfrag];
            ubl[nt][ks] = *(const bx8*)&U[c * UPAD + 64 + ks * 32 + kfrag];
        }
    }

    // M1: SE = V2 @ U   (split: Vh*Uh + Vh*Ul + Vl*Uh)
    {
        fx4 acc[4][2];
        #pragma unroll
        for (int mt = 0; mt < 4; ++mt)
            #pragma unroll
            for (int nt = 0; nt < 2; ++nt) { fx4 z = {0.f,0.f,0.f,0.f}; acc[mt][nt] = z; }
        #pragma unroll
        for (int mt = 0; mt < 4; ++mt) {
            #pragma unroll
            for (int ks = 0; ks < 2; ++ks) {
                int ao = (mt * 16 + arow_lo) * 64 + ks * 32 + kfrag;
                bx8 vh = *(const bx8*)&pm[PM_V2H + ao];
                bx8 vl = *(const bx8*)&pm[PM_V2L + ao];
                #pragma unroll
                for (int nt = 0; nt < 2; ++nt) {
                    acc[mt][nt] = __builtin_amdgcn_mfma_f32_16x16x32_bf16(vh, ubh[nt][ks], acc[mt][nt], 0, 0, 0);
                    acc[mt][nt] = __builtin_amdgcn_mfma_f32_16x16x32_bf16(vh, ubl[nt][ks], acc[mt][nt], 0, 0, 0);
                    acc[mt][nt] = __builtin_amdgcn_mfma_f32_16x16x32_bf16(vl, ubh[nt][ks], acc[mt][nt], 0, 0, 0);
                }
            }
        }
        // write SE bf16: row = state index, col = chunk
        #pragma unroll
        for (int mt = 0; mt < 4; ++mt)
            #pragma unroll
            for (int nt = 0; nt < 2; ++nt) {
                int c = cb + nt * 16;
                int row = mt * 16 + (lane >> 4) * 4;
                #pragma unroll
                for (int r = 0; r < 4; ++r)
                    SES[c * SPAD + row + r] = f2us(acc[mt][nt][r]);
            }
    }
    __syncthreads();

    // serial carry scan over chunks; overwrite SES with carry-in (S0) per chunk
    if (tid < 32) {
        const int d3 = tid >> 4, n = tid & 15;
        float wSr = P[OFF_WSR + h * NN + n], wSi = P[OFF_WSI + h * NN + n];
        const int kk = d3 * 32 + 2 * n;
        float cr = 0.f, ci = 0.f;
        if (d3 == 0) {
            for (int q = 0; q < CHN; ++q) {
                unsigned* p = (unsigned*)&SES[q * SPAD + kk];
                unsigned pv = *p;
                float fr = lo2f(pv), fi = hi2f(pv);
                *p = pack2(cr, ci);
                float nr2 = fmaf(wSr, cr, fmaf(-wSi, ci, fr));
                float ni2 = fmaf(wSr, ci, fmaf(wSi, cr, fi));
                cr = nr2; ci = ni2;
            }
        } else {
            for (int q = CHN - 1; q >= 0; --q) {
                unsigned* p = (unsigned*)&SES[q * SPAD + kk];
                unsigned pv = *p;
                float fr = lo2f(pv), fi = hi2f(pv);
                *p = pack2(cr, ci);
                float nr2 = fmaf(wSr, cr, fmaf(-wSi, ci, fr));
                float ni2 = fmaf(wSr, ci, fmaf(wSi, cr, fi));
                cr = nr2; ci = ni2;
            }
        }
    }
    __syncthreads();

    // M2: Y = T @ U + CW @ S0
    {
        bx8 sb[2][2];
        #pragma unroll
        for (int nt = 0; nt < 2; ++nt) {
            int c = cb + nt * 16;
            #pragma unroll
            for (int ks = 0; ks < 2; ++ks)
                sb[nt][ks] = *(const bx8*)&SES[c * SPAD + ks * 32 + kfrag];
        }
        fx4 acc[4][2];
        #pragma unroll
        for (int mt = 0; mt < 4; ++mt)
            #pragma unroll
            for (int nt = 0; nt < 2; ++nt) { fx4 z = {0.f,0.f,0.f,0.f}; acc[mt][nt] = z; }
        #pragma unroll
        for (int mt = 0; mt < 4; ++mt) {
            #pragma unroll
            for (int ks = 0; ks < 2; ++ks) {
                int ao = (mt * 16 + arow_lo) * 64 + ks * 32 + kfrag;
                bx8 th = *(const bx8*)&pm[PM_TH + ao];
                bx8 tl = *(const bx8*)&pm[PM_TL + ao];
                bx8 ch = *(const bx8*)&pm[PM_CWH + ao];
                bx8 cl = *(const bx8*)&pm[PM_CWL + ao];
                #pragma unroll
                for (int nt = 0; nt < 2; ++nt) {
                    acc[mt][nt] = __builtin_amdgcn_mfma_f32_16x16x32_bf16(th, ubh[nt][ks], acc[mt][nt], 0, 0, 0);
                    acc[mt][nt] = __builtin_amdgcn_mfma_f32_16x16x32_bf16(th, ubl[nt][ks], acc[mt][nt], 0, 0, 0);
                    acc[mt][nt] = __builtin_amdgcn_mfma_f32_16x16x32_bf16(tl, ubh[nt][ks], acc[mt][nt], 0, 0, 0);
                    acc[mt][nt] = __builtin_amdgcn_mfma_f32_16x16x32_bf16(ch, sb[nt][ks], acc[mt][nt], 0, 0, 0);
                    acc[mt][nt] = __builtin_amdgcn_mfma_f32_16x16x32_bf16(cl, sb[nt][ks], acc[mt][nt], 0, 0, 0);
                }
            }
        }
        // finalize: gelu, store
        #pragma unroll
        for (int mt = 0; mt < 4; ++mt)
            #pragma unroll
            for (int nt = 0; nt < 2; ++nt) {
                int c = cb + nt * 16;
                float4 ov;
                #pragma unroll
                for (int r = 0; r < 4; ++r)
                    (&ov.x)[r] = gelu_tanh(acc[mt][nt][r]);
                *(float4*)&yrow[c * 64 + mt * 16 + (lane >> 4) * 4] = ov;
            }
    }
}

// ---- GLU output projection via split-bf16 MFMA.
__global__ __launch_bounds__(256, 2) void gemm_glu_mfma(
    const u16* __restrict__ Whi, const u16* __restrict__ Wlo,
    const float* __restrict__ Y, const float* __restrict__ bias,
    const float* __restrict__ xres, float* __restrict__ out)
{
    __shared__ __align__(16) char smem[65536];
    u16* Ah = (u16*)smem;
    u16* Al = Ah + 8192;
    u16* Bh = Al + 8192;
    u16* Bl = Bh + 8192;

    const int tid  = threadIdx.x;
    const int lane = tid & 63;
    const int wv   = tid >> 6;
    const int wrh  = wv & 1;
    const int wch  = wv >> 1;
    const int bz   = blockIdx.z;
    const int l0   = blockIdx.x * 128;
    const int c0   = blockIdx.y * 64;

    fx4 acc[4][4];
    #pragma unroll
    for (int i = 0; i < 4; ++i)
        #pragma unroll
        for (int j = 0; j < 4; ++j) {
            fx4 z = {0.f, 0.f, 0.f, 0.f};
            acc[i][j] = z;
        }

    const int am  = tid & 127;
    const int akh = tid >> 7;
    const int aorow = (am < 64) ? (c0 + am) : (c0 + 256 + (am - 64));
    const int amt = am >> 4, amm = am & 15;

    const int bli = (tid & 63) + ((tid >> 6) & 1) * 64;
    const int bkh = tid >> 7;
    const int bnt = bli >> 4, bcol = bli & 15;

    const float* Yb = Y + (size_t)bz * HH * LL + l0;

    for (int k0 = 0; k0 < 256; k0 += 64) {
        #pragma unroll
        for (int oct = 0; oct < 4; ++oct) {
            int k = k0 + akh * 32 + oct * 8;
            int4 vh = *(const int4*)&Whi[(size_t)aorow * 256 + k];
            int4 vl = *(const int4*)&Wlo[(size_t)aorow * 256 + k];
            int base = ((akh * 8 + amt) * 64 + amm + (oct << 4)) * 8;
            *(int4*)&Ah[base] = vh;
            *(int4*)&Al[base] = vl;
        }
        #pragma unroll
        for (int oct = 0; oct < 4; ++oct) {
            int kb = k0 + bkh * 32 + oct * 8;
            float v[8];
            #pragma unroll
            for (int j = 0; j < 8; ++j)
                v[j] = Yb[(size_t)(kb + j) * LL + bli];
            u16 h8[8], l8[8];
            #pragma unroll
            for (int j = 0; j < 8; ++j) {
                __hip_bfloat16 hb = f2b(v[j]);
                h8[j] = *reinterpret_cast<u16*>(&hb);
                l8[j] = f2us(v[j] - b2f(hb));
            }
            int base = ((bkh * 8 + bnt) * 64 + bcol + (oct << 4)) * 8;
            *(int4*)&Bh[base] = *(const int4*)h8;
            *(int4*)&Bl[base] = *(const int4*)l8;
        }
        __syncthreads();
        #pragma unroll
        for (int ks = 0; ks < 2; ++ks) {
            bx8 bh[4], bl[4];
            #pragma unroll
            for (int nt = 0; nt < 4; ++nt) {
                int base = ((ks * 8 + wch * 4 + nt) * 64 + lane) * 8;
                bh[nt] = *(const bx8*)&Bh[base];
                bl[nt] = *(const bx8*)&Bl[base];
            }
            #pragma unroll
            for (int mt = 0; mt < 4; ++mt) {
                int base = ((ks * 8 + wrh * 4 + mt) * 64 + lane) * 8;
                bx8 ah = *(const bx8*)&Ah[base];
                bx8 al = *(const bx8*)&Al[base];
                #pragma unroll
                for (int nt = 0; nt < 4; ++nt) {
                    acc[mt][nt] = __builtin_amdgcn_mfma_f32_16x16x32_bf16(ah, bh[nt], acc[mt][nt], 0, 0, 0);
                    acc[mt][nt] = __builtin_amdgcn_mfma_f32_16x16x32_bf16(ah, bl[nt], acc[mt][nt], 0, 0, 0);
                    acc[mt][nt] = __builtin_amdgcn_mfma_f32_16x16x32_bf16(al, bh[nt], acc[mt][nt], 0, 0, 0);
                }
            }
        }
        __syncthreads();
    }

    float* zbuf = (float*)smem;
    if (wrh == 1) {
        #pragma unroll
        for (int mt = 0; mt < 4; ++mt) {
            int mloc = mt * 16 + (lane >> 4) * 4;
            float b1v[4];
            #pragma unroll
            for (int r = 0; r < 4; ++r) b1v[r] = bias[c0 + 256 + mloc + r];
            #pragma unroll
            for (int nt = 0; nt < 4; ++nt) {
                int nloc = nt * 16 + (lane & 15);
                #pragma unroll
                for (int r = 0; r < 4; ++r)
                    zbuf[wch * 4160 + (mloc + r) * 65 + nloc] = acc[mt][nt][r] + b1v[r];
            }
        }
    }
    __syncthreads();
    if (wrh == 0) {
        #pragma unroll
        for (int mt = 0; mt < 4; ++mt) {
            int mloc = mt * 16 + (lane >> 4) * 4;
            float b0v[4];
            #pragma unroll
            for (int r = 0; r < 4; ++r) b0v[r] = bias[c0 + mloc + r];
            #pragma unroll
            for (int nt = 0; nt < 4; ++nt) {
                int nloc = nt * 16 + (lane & 15);
                int l = l0 + wch * 64 + nloc;
                #pragma unroll
                for (int r = 0; r < 4; ++r) {
                    float z1 = zbuf[wch * 4160 + (mloc + r) * 65 + nloc];
                    float z0 = acc[mt][nt][r] + b0v[r];
                    size_t ga = ((size_t)bz * HH + c0 + mloc + r) * LL + l;
                    out[ga] = z0 * sigmoid_(z1) + xres[ga];
                }
            }
        }
    }
}

template<int MODE, int WLD>
__global__ __launch_bounds__(256, 3) void gemm_mfma(
    const u16* __restrict__ Aw, const u16* __restrict__ Bm,
    const float* bias, const float* resid, void* outv)
{
    __shared__ __align__(16) char smem[33792];
    u16*   Alds = (u16*)smem;
    u16*   Blds = (u16*)(smem + 16384);
    float* Eps  = (float*)smem;
    u16*   TT   = (u16*)smem;

    const int tid  = threadIdx.x;
    const int lane = tid & 63;
    const int wv   = tid >> 6;
    const int wr   = wv >> 1, wc = wv & 1;
    const int bz   = blockIdx.z;
    const int l0   = blockIdx.x * 128;
    const int mbase = blockIdx.y * 128;

    fx4 acc[4][4];
    #pragma unroll
    for (int i = 0; i < 4; ++i)
        #pragma unroll
        for (int j = 0; j < 4; ++j) {
            fx4 z = {0.f, 0.f, 0.f, 0.f};
            acc[i][j] = z;
        }

    const size_t brow0 = (size_t)bz * LL;
    for (int k0 = 0; k0 < 256; k0 += 64) {
        #pragma unroll
        for (int i = 0; i < 4; ++i) {
            int f = tid + i * 256;
            int mm = f & 15, kg = (f >> 4) & 3, m16 = (f >> 6) & 7, ks = f >> 9;
            int k = k0 + ks * 32 + kg * 8;
            int o = mbase + m16 * 16 + mm;
            int4 wv4 = *(const int4*)(Aw + (size_t)o * WLD + k);
            *(int4*)&Alds[f * 8] = wv4;
            int row = l0 + m16 * 16 + mm;
            int4 xv4 = *(const int4*)(Bm + (brow0 + row) * 256 + k);
            *(int4*)&Blds[f * 8] = xv4;
        }
        __syncthreads();
        #pragma unroll
        for (int ks = 0; ks < 2; ++ks) {
            bx8 av[4], bv[4];
            #pragma unroll
            for (int mt = 0; mt < 4; ++mt)
                av[mt] = *(const bx8*)&Alds[(ks * 512 + (wr * 4 + mt) * 64 + lane) * 8];
            #pragma unroll
            for (int nt = 0; nt < 4; ++nt)
                bv[nt] = *(const bx8*)&Blds[(ks * 512 + (wc * 4 + nt) * 64 + lane) * 8];
            #pragma unroll
            for (int mt = 0; mt < 4; ++mt)
                #pragma unroll
                for (int nt = 0; nt < 4; ++nt)
                    acc[mt][nt] = __builtin_amdgcn_mfma_f32_16x16x32_bf16(
                        av[mt], bv[nt], acc[mt][nt], 0, 0, 0);
        }
        __syncthreads();
    }

    if (MODE == 1) {
        u16* hT = (u16*)outv;
        #pragma unroll
        for (int p = 0; p < 2; ++p) {
            if (p) __syncthreads();
            if (wc == p) {
                #pragma unroll
                for (int mt = 0; mt < 4; ++mt) {
                    int mb = wr * 64 + mt * 16 + (lane >> 4) * 4;
                    float bvv[4];
                    #pragma unroll
                    for (int r = 0; r < 4; ++r) bvv[r] = bias[mbase + mb + r];
                    #pragma unroll
                    for (int nt = 0; nt < 4; ++nt) {
                        int n = nt * 16 + (lane & 15);
                        u16 pk[4];
                        #pragma unroll
                        for (int r = 0; r < 4; ++r)
                            pk[r] = f2us(gelu_tanh(acc[mt][nt][r] + bvv[r]));
                        *(ushort4*)&TT[n * 136 + mb] = *(const ushort4*)pk;
                    }
                }
            }
            __syncthreads();
            #pragma unroll
            for (int i = 0; i < 4; ++i) {
                int idx = tid + i * 256;
                int l = idx >> 4, c = idx & 15;
                int4 v = *(const int4*)&TT[l * 136 + c * 8];
                *(int4*)&hT[((size_t)bz * LL + l0 + p * 64 + l) * 256 + mbase + c * 8] = v;
            }
        }
    } else {
        float* outp = (float*)outv;
        #pragma unroll
        for (int p = 0; p < 2; ++p) {
            if (p) __syncthreads();
            if (wc == p) {
                #pragma unroll
                for (int mt = 0; mt < 4; ++mt)
                    #pragma unroll
                    for (int nt = 0; nt < 4; ++nt) {
                        int m = wr * 64 + mt * 16 + (lane >> 4) * 4;
                        int n = nt * 16 + (lane & 15);
                        #pragma unroll
                        for (int r = 0; r < 4; ++r)
                            Eps[(m + r) * 66 + n] = acc[mt][nt][r];
                    }
            }
            __syncthreads();
            #pragma unroll
            for (int i = 0; i < 8; ++i) {
                int idx = tid + i * 256;
                int r = idx >> 4, lq = idx & 15;
                float bv = bias ? bias[mbase + r] : 0.f;
                size_t ga = ((size_t)bz * HH + mbase + r) * LL + l0 + p * 64 + lq * 4;
                float4 rv = *(const float4*)&resid[ga];
                float4 ov;
                #pragma unroll
                for (int j = 0; j < 4; ++j)
                    (&ov.x)[j] = Eps[r * 66 + lq * 4 + j] + bv + (&rv.x)[j];
                *(float4*)&outp[ga] = ov;
            }
        }
    }
}

extern "C" void kernel_launch(void* const* d_in, const int* in_sizes, int n_in,
                              void* d_out, int out_size, void* d_ws, size_t ws_size,
                              hipStream_t stream) {
    (void)in_sizes; (void)n_in; (void)out_size; (void)ws_size;
    const float* x      = (const float*)d_in[0];
    const float* emb    = (const float*)d_in[1];
    const float* fc_t_w = (const float*)d_in[2];
    const float* fc_t_b = (const float*)d_in[3];
    const float* log_dt = (const float*)d_in[4];
    const float* A_re   = (const float*)d_in[5];
    const float* A_im   = (const float*)d_in[6];
    const float* C_re   = (const float*)d_in[7];
    const float* C_im   = (const float*)d_in[8];
    const float* Dp     = (const float*)d_in[9];
    const float* out_w  = (const float*)d_in[10];
    const float* out_b  = (const float*)d_in[11];
    const float* n1_m   = (const float*)d_in[12];
    const float* n1_s   = (const float*)d_in[13];
    const float* n2_m   = (const float*)d_in[14];
    const float* n2_s   = (const float*)d_in[15];
    const float* ff_w1  = (const float*)d_in[16];
    const float* ff_b1  = (const float*)d_in[17];
    const float* ff_w2  = (const float*)d_in[18];
    const float* ff_b2  = (const float*)d_in[19];
    float* outp = (float*)d_out;

    // Workspace map (floats, total 2*BHL = 128 MiB):
    //   region A [0, BHL):              u fp32 -> ys4 (scan in place) -> t2T bf16
    //   region B [BHL, BHL+BHL/2):      hT bf16 (ends at 97.6MB) ... PM at 1.5*BHL (12MB)
    //   WP corner [2*BHL-512K floats):  bf16 weights + P
    float* wsf  = (float*)d_ws;
    float* u    = wsf;
    u16*   t2T  = (u16*)wsf;
    u16*   hT   = (u16*)(wsf + BHL);
    u16*   PM   = (u16*)(wsf + BHL + BHL / 2);      // 256*24576 u16 = 12 MB
    constexpr size_t WPOFF = 2 * BHL - 524288;
    u16*   W1c  = (u16*)(wsf + WPOFF);              // 512*256 bf16
    u16*   W2c  = W1c + 131072;                     // 256*512 bf16
    u16*   WOh  = W2c + 131072;                     // out_w hi 512*256 bf16
    u16*   WOl  = WOh + 131072;                     // out_w lo 512*256 bf16
    float* P    = wsf + WPOFF + 262144;             // 34,816 floats

    setup_s4_params<<<16, 256, 0, stream>>>(log_dt, A_re, A_im, C_re, C_im, P);
    part_t_kernel<<<8, 256, 0, stream>>>(emb, fc_t_w, fc_t_b, P);
    setup_scan_mats<<<HH, 64, 0, stream>>>(P, Dp, PM);
    convert_w_kernel<<<512, 256, 0, stream>>>(ff_w1, W1c, 512 * 256);
    convert_w_kernel<<<512, 256, 0, stream>>>(ff_w2, W2c, 256 * 512);
    convert_w_split<<<512, 256, 0, stream>>>(out_w, WOh, WOl, 512 * 256);

    // u = TLN1(x) + part_t
    tln_kernel<<<dim3(LL / 64, BB), 256, 0, stream>>>(x, u, n1_m, n1_s, P + OFF_PT);

    // ys4 = gelu(S4_bidir(u) + u*D), in place over u  (MFMA formulation)
    scan_mfma<<<BB * HH, 256, 0, stream>>>(u, P, PM, u);

    // res = x + GLU(out_w @ ys4 + out_b) -> d_out
    gemm_glu_mfma<<<dim3(LL / 128, 4, BB), 256, 0, stream>>>(WOh, WOl, u, out_b, x, outp);

    // t2T = TLN2(res) transposed bf16
    tln2t_kernel<<<dim3(LL / 64, BB), 256, 0, stream>>>(outp, t2T, n2_m, n2_s);

    // FF in two hidden halves; hT half = 32 MB in region B
    gemm_mfma<1, 256><<<dim3(LL / 128, 2, BB), 256, 0, stream>>>(W1c, t2T, ff_b1, nullptr, hT);
    gemm_mfma<2, 512><<<dim3(LL / 128, 2, BB), 256, 0, stream>>>(W2c, hT, ff_b2, outp, outp);
    gemm_mfma<1, 256><<<dim3(LL / 128, 2, BB), 256, 0, stream>>>(W1c + 65536, t2T, ff_b1 + 256, nullptr, hT);
    gemm_mfma<2, 512><<<dim3(LL / 128, 2, BB), 256, 0, stream>>>(W2c + 256, hT, nullptr, outp, outp);
}